// Round 4
// baseline (2825.679 us; speedup 1.0000x reference)
//
#include <hip/hip_runtime.h>
#include <hip/hip_bf16.h>

// Problem constants: B=16, T=512, E=1024, H=512, 3H=1536, E+H=1536.
//
// R4 change: tag-in-data h exchange. R3's chain was 4-5 IF round-trips +
// a 32-way serialized flag RMW on one line (~12k cyc/step). Now h is stored
// as u32 = (step_tag<<16)|bf16 into an 8-slot ring; producers fire-and-forget
// 4 relaxed-agent stores (no drain/flag/RMW); consumers spin on 64 pipelined
// relaxed-agent u64 loads + ballot tag check — the data load IS the poll.
// Chain/step ~= store flight + 1.5 retry RTT + compute.

typedef __attribute__((ext_vector_type(8))) short s8v;
typedef __attribute__((ext_vector_type(4))) short s4v;
typedef __attribute__((ext_vector_type(4))) float f4v;
typedef __attribute__((ext_vector_type(4))) unsigned short us4;
typedef unsigned long long u64;
typedef unsigned int u32;

// ws layout (bytes)
#define XBF_OFF   0ull          // 8192*1024*2        = 16,777,216
#define WXBF_OFF  16777216ull   // 3072*1024*2        =  6,291,456
#define WHBF_OFF  23068672ull   // 2*1536*512*2       =  3,145,728
#define XG_OFF    26214400ull   // 2*512*1536*16*2    = 50,331,648
#define HST_OFF   76546048ull   // 2*8*16*512*4 (u32 ring) = 524,288

static __device__ __forceinline__ short f2bf(float f) {
  __hip_bfloat16 h = __float2bfloat16(f);
  return *reinterpret_cast<short*>(&h);
}
static __device__ __forceinline__ float bf2f(unsigned short u) {
  union { unsigned int i; float f; } x;
  x.i = ((unsigned int)u) << 16;
  return x.f;
}
static __device__ __forceinline__ float sigmoidf_(float x) {
  return 1.0f / (1.0f + __expf(-x));
}
static __device__ __forceinline__ float tanhf_(float x) {
  return 1.0f - 2.0f / (1.0f + __expf(2.0f * x));
}

// ---------------- init: ring slot 0 = h0 tagged step 0 -----------------
__global__ void init_state(const float* __restrict__ h0f, const float* __restrict__ h0b,
                           u32* __restrict__ hst) {
  int i = blockIdx.x * 256 + threadIdx.x;
  if (i < 2 * 16 * 512) {
    int dir = i >> 13;
    int r = i & 8191;       // b*512 + col
    int col = r & 511;
    const float* h0 = dir ? h0b : h0f;
    // tag 0 in high 16, bf16 in low 16
    hst[(size_t)dir * 8 * 8192 + r] = (u32)(unsigned short)f2bf(h0[col]);
  }
}

// ---------------- cast x to bf16 ----------------
__global__ void cast_x(const float* __restrict__ x, short* __restrict__ xb) {
  int i = (blockIdx.x * 256 + threadIdx.x) * 4;
  f4v v = *reinterpret_cast<const f4v*>(x + i);
  s4v o;
#pragma unroll
  for (int j = 0; j < 4; ++j) o[j] = f2bf(v[j]);
  *reinterpret_cast<s4v*>(xb + i) = o;
}

// ---------------- cast/split weights ----------------
__global__ void cast_w(const float* __restrict__ wf, const float* __restrict__ wb,
                       short* __restrict__ wxb, short* __restrict__ whb) {
  int e = blockIdx.x * 256 + threadIdx.x;  // < 1536*1536
  int dir = blockIdx.y;
  const float* w = dir ? wb : wf;
  int n = e / 1536;
  int k = e - n * 1536;
  short v = f2bf(w[e]);
  if (k < 1024)
    wxb[((size_t)(dir * 1536 + n)) * 1024 + k] = v;
  else
    whb[((size_t)(dir * 1536 + n)) * 512 + (k - 1024)] = v;
}

// ---------------- input GEMM: C = Xb @ Wxb^T, scattered to Xg[dir][t][ng][b] ----
__global__ __launch_bounds__(256) void gemm_in(const short* __restrict__ Xb,
                                               const short* __restrict__ Wxb,
                                               short* __restrict__ Xg) {
  __shared__ short As[128 * 72];
  __shared__ short Bs[128 * 72];
  int tid = threadIdx.x;
  int lane = tid & 63;
  int lr = lane & 15, quad = lane >> 4;
  int widx = tid >> 6;
  int wr = widx >> 1, wc = widx & 1;
  int bm = blockIdx.x, bn = blockIdx.y;

  f4v acc[4][4];
#pragma unroll
  for (int a = 0; a < 4; ++a)
#pragma unroll
    for (int b = 0; b < 4; ++b) acc[a][b] = {0.f, 0.f, 0.f, 0.f};

  const short* Arow = Xb + (size_t)bm * 128 * 1024;
  const short* Brow = Wxb + (size_t)bn * 128 * 1024;

  for (int kt = 0; kt < 16; ++kt) {
#pragma unroll
    for (int c = 0; c < 4; ++c) {
      int fl = c * 2048 + tid * 8;
      int row = fl >> 6, col = fl & 63;
      *reinterpret_cast<s8v*>(&As[row * 72 + col]) =
          *reinterpret_cast<const s8v*>(Arow + row * 1024 + kt * 64 + col);
      *reinterpret_cast<s8v*>(&Bs[row * 72 + col]) =
          *reinterpret_cast<const s8v*>(Brow + row * 1024 + kt * 64 + col);
    }
    __syncthreads();
#pragma unroll
    for (int kk = 0; kk < 2; ++kk) {
      s8v af[4], bfv[4];
#pragma unroll
      for (int mi = 0; mi < 4; ++mi)
        af[mi] = *reinterpret_cast<const s8v*>(&As[(wr * 64 + mi * 16 + lr) * 72 + kk * 32 + quad * 8]);
#pragma unroll
      for (int ni = 0; ni < 4; ++ni)
        bfv[ni] = *reinterpret_cast<const s8v*>(&Bs[(wc * 64 + ni * 16 + lr) * 72 + kk * 32 + quad * 8]);
#pragma unroll
      for (int mi = 0; mi < 4; ++mi)
#pragma unroll
        for (int ni = 0; ni < 4; ++ni)
          acc[mi][ni] = __builtin_amdgcn_mfma_f32_16x16x32_bf16(af[mi], bfv[ni], acc[mi][ni], 0, 0, 0);
    }
    __syncthreads();
  }

  int ngbase = bn * 128;
  int dir = (ngbase >= 1536) ? 1 : 0;
  int ng0 = ngbase - dir * 1536;
#pragma unroll
  for (int mi = 0; mi < 4; ++mi) {
#pragma unroll
    for (int ni = 0; ni < 4; ++ni) {
      int colg = ng0 + wc * 64 + ni * 16 + lr;
#pragma unroll
      for (int r = 0; r < 4; ++r) {
        int m = bm * 128 + wr * 64 + mi * 16 + quad * 4 + r;  // m = b*512 + t
        int b = m >> 9, t = m & 511;
        Xg[(((size_t)(dir * 512 + t)) * 1536 + colg) * 16 + b] = f2bf(acc[mi][ni][r]);
      }
    }
  }
}

// ---------------- recurrence ----------------
// 64 blocks x 64 threads (1 wave each); wave wg=blockIdx: dir=wg>>5, slice=wg&31.
// Wave owns h-cols [16*slice,16*slice+16). Wh in 192 VGPRs. h exchanged through
// an 8-slot u32 ring at agent scope (IF-served); tag-in-data, no flags.
__global__ __launch_bounds__(64, 1) void lstm_rec(
    const short* __restrict__ Whb, const short* __restrict__ Xg,
    const float* __restrict__ bfw, const float* __restrict__ bbw,
    const float* __restrict__ c0f, const float* __restrict__ c0b,
    u32* __restrict__ hst, float* __restrict__ out) {
  int lane = threadIdx.x & 63;
  int lr = lane & 15, quad = lane >> 4;
  int wg = blockIdx.x;
  int dir = wg >> 5;
  int slice = wg & 31;
  int col16 = slice * 16;

  // Persistent B fragments (normal cached loads)
  const short* Whd = Whb + (size_t)dir * 1536 * 512;
  s8v Bw[3][16];
#pragma unroll
  for (int g = 0; g < 3; ++g) {
    const short* rp = Whd + (size_t)(g * 512 + col16 + lr) * 512 + quad * 8;
#pragma unroll
    for (int k = 0; k < 16; ++k) Bw[g][k] = *reinterpret_cast<const s8v*>(rp + k * 32);
  }

  const float* bias = dir ? bbw : bfw;
  float bi = bias[col16 + lr];
  float bj = bias[512 + col16 + lr];
  float bo = bias[1024 + col16 + lr];

  const float* c0 = dir ? c0b : c0f;
  float cst[4];
  {
    float c0v = c0[col16 + lr];
#pragma unroll
    for (int r = 0; r < 4; ++r) cst[r] = c0v;
  }

  u32* hring = hst + (size_t)dir * 8 * 8192;  // 8 frames of 16x512 u32
  const short* xgbase = Xg + (size_t)dir * 512 * 1536 * 16;

  // Consumer u64 index into a frame: row lr (256 u64), col block quad*8 u32 (4 u64)
  int hqidx = lr * 256 + quad * 4;

  // First Xg prefetch (t for s=0)
  int t0 = dir ? 511 : 0;
  const short* xgp = xgbase + (size_t)t0 * 1536 * 16;
  us4 xiv = *reinterpret_cast<const us4*>(xgp + (col16 + lr) * 16 + quad * 4);
  us4 xjv = *reinterpret_cast<const us4*>(xgp + (512 + col16 + lr) * 16 + quad * 4);
  us4 xov = *reinterpret_cast<const us4*>(xgp + (1024 + col16 + lr) * 16 + quad * 4);

  for (int s = 0; s < 512; ++s) {
    int t = dir ? (511 - s) : s;

    // --- acquire h(s): retry gather of tagged frame (the load IS the poll) ---
    const u64* hq = reinterpret_cast<const u64*>(hring + (size_t)(s & 7) * 8192);
    u64 qa[64];
    for (;;) {
#pragma unroll
      for (int k = 0; k < 16; ++k) {
#pragma unroll
        for (int h2 = 0; h2 < 4; ++h2)
          qa[k * 4 + h2] = __hip_atomic_load(hq + hqidx + k * 16 + h2,
                                             __ATOMIC_RELAXED, __HIP_MEMORY_SCOPE_AGENT);
      }
      u64 ok = ~0ull;
#pragma unroll
      for (int k = 0; k < 64; ++k)
        ok &= __ballot((u32)(qa[k] >> 48) == (u32)s);
      if (ok == ~0ull) break;
    }

    // --- pack bf16 fragments and MFMA ---
    f4v a0 = {0.f, 0.f, 0.f, 0.f};
    f4v a1 = {0.f, 0.f, 0.f, 0.f};
    f4v a2 = {0.f, 0.f, 0.f, 0.f};
#pragma unroll
    for (int k = 0; k < 16; ++k) {
      union { u32 u[4]; s8v v; } f;
#pragma unroll
      for (int j = 0; j < 4; ++j) {
        u64 q = qa[k * 4 + j];
        f.u[j] = __builtin_amdgcn_perm((u32)(q >> 32), (u32)q, 0x05040100u);
      }
      a0 = __builtin_amdgcn_mfma_f32_16x16x32_bf16(f.v, Bw[0][k], a0, 0, 0, 0);
      a1 = __builtin_amdgcn_mfma_f32_16x16x32_bf16(f.v, Bw[1][k], a1, 0, 0, 0);
      a2 = __builtin_amdgcn_mfma_f32_16x16x32_bf16(f.v, Bw[2][k], a2, 0, 0, 0);
    }

    // --- elementwise + fire-and-forget tagged h stores ---
    u32* hdst = hring + (size_t)((s + 1) & 7) * 8192;
    u32 tagn = (u32)(s + 1) << 16;
    float hn[4];
#pragma unroll
    for (int r = 0; r < 4; ++r) {
      float gi = a0[r] + bf2f(xiv[r]) + bi;
      float gj = a1[r] + bf2f(xjv[r]) + bj;
      float go = a2[r] + bf2f(xov[r]) + bo;
      float ii = sigmoidf_(gi);
      float jt = tanhf_(gj);
      float oo = sigmoidf_(go);
      cst[r] = (1.0f - ii) * cst[r] + ii * jt;
      hn[r] = tanhf_(cst[r]) * oo;
      u32 hv = tagn | (u32)(unsigned short)f2bf(hn[r]);
      __hip_atomic_store(hdst + (quad * 4 + r) * 512 + col16 + lr, hv,
                         __ATOMIC_RELAXED, __HIP_MEMORY_SCOPE_AGENT);
    }

    // --- off-critical-path: output store + next-step Xg prefetch ---
#pragma unroll
    for (int r = 0; r < 4; ++r)
      out[((size_t)(quad * 4 + r) * 512 + t) * 1024 + dir * 512 + col16 + lr] = hn[r];

    if (s < 511) {
      int tn = dir ? (511 - (s + 1)) : (s + 1);
      const short* xgn = xgbase + (size_t)tn * 1536 * 16;
      xiv = *reinterpret_cast<const us4*>(xgn + (col16 + lr) * 16 + quad * 4);
      xjv = *reinterpret_cast<const us4*>(xgn + (512 + col16 + lr) * 16 + quad * 4);
      xov = *reinterpret_cast<const us4*>(xgn + (1024 + col16 + lr) * 16 + quad * 4);
    }
  }
}

extern "C" void kernel_launch(void* const* d_in, const int* in_sizes, int n_in,
                              void* d_out, int out_size, void* d_ws, size_t ws_size,
                              hipStream_t stream) {
  const float* x    = (const float*)d_in[0];
  const float* wfw  = (const float*)d_in[1];
  const float* bfw  = (const float*)d_in[2];
  const float* wbw  = (const float*)d_in[3];
  const float* bbw  = (const float*)d_in[4];
  const float* h0f  = (const float*)d_in[5];
  const float* h0b  = (const float*)d_in[6];
  const float* c0f  = (const float*)d_in[7];
  const float* c0b  = (const float*)d_in[8];
  float* out = (float*)d_out;

  unsigned char* ws = (unsigned char*)d_ws;
  short* Xbf  = (short*)(ws + XBF_OFF);
  short* Wxbf = (short*)(ws + WXBF_OFF);
  short* Whbf = (short*)(ws + WHBF_OFF);
  short* Xg   = (short*)(ws + XG_OFF);
  u32*   hst  = (u32*)(ws + HST_OFF);

  init_state<<<64, 256, 0, stream>>>(h0f, h0b, hst);
  cast_x<<<8192, 256, 0, stream>>>(x, Xbf);
  cast_w<<<dim3(9216, 2), 256, 0, stream>>>(wfw, wbw, Wxbf, Whbf);
  gemm_in<<<dim3(64, 24), 256, 0, stream>>>(Xbf, Wxbf, Xg);
  lstm_rec<<<64, 64, 0, stream>>>(Whbf, Xg, bfw, bbw, c0f, c0b, hst, out);
}

// Round 5
// 1787.839 us; speedup vs baseline: 1.5805x; 1.5805x over previous
//
#include <hip/hip_runtime.h>
#include <hip/hip_bf16.h>

// Problem constants: B=16, T=512, E=1024, H=512, 3H=1536, E+H=1536.
//
// R5: split detect from fetch. Per-slice tag words (one IF line per dir):
// producer: 4 bf16 h stores (asm sc0sc1) -> vmcnt(0) -> relaxed-agent tag=s+1.
// consumer: 1-load tag poll + ballot (retry period ~1 RTT), then one asm block
// of 16 pipelined global_load_dwordx4 sc0sc1 (single RTT bulk fetch). Frames
// are plain bf16 (16 KB, 4-slot ring) - no perm unpack, no retry re-read of
// bulk data (R4's failure: 64 atomic loads chunked by RA -> 3-4 serial RTTs).

typedef __attribute__((ext_vector_type(8))) short s8v;
typedef __attribute__((ext_vector_type(4))) short s4v;
typedef __attribute__((ext_vector_type(4))) float f4v;
typedef __attribute__((ext_vector_type(4))) unsigned short us4;
typedef unsigned long long u64;
typedef unsigned int u32;

// ws layout (bytes)
#define XBF_OFF   0ull          // 8192*1024*2        = 16,777,216
#define WXBF_OFF  16777216ull   // 3072*1024*2        =  6,291,456
#define WHBF_OFF  23068672ull   // 2*1536*512*2       =  3,145,728
#define XG_OFF    26214400ull   // 2*512*1536*16*2    = 50,331,648
#define HST_OFF   76546048ull   // 2 dirs * 4 slots * 16KB bf16 frames = 131,072
#define TAG_OFF   76677120ull   // 2*32*4 = 256

static __device__ __forceinline__ short f2bf(float f) {
  __hip_bfloat16 h = __float2bfloat16(f);
  return *reinterpret_cast<short*>(&h);
}
static __device__ __forceinline__ float bf2f(unsigned short u) {
  union { unsigned int i; float f; } x;
  x.i = ((unsigned int)u) << 16;
  return x.f;
}
static __device__ __forceinline__ float sigmoidf_(float x) {
  return 1.0f / (1.0f + __expf(-x));
}
static __device__ __forceinline__ float tanhf_(float x) {
  return 1.0f - 2.0f / (1.0f + __expf(2.0f * x));
}

// ---------------- init: ring slot 0 = h0 (bf16), tags = 0 -----------------
__global__ void init_state(const float* __restrict__ h0f, const float* __restrict__ h0b,
                           short* __restrict__ hst, u32* __restrict__ tags) {
  int i = blockIdx.x * 256 + threadIdx.x;
  if (i < 2 * 16 * 512) {
    int dir = i >> 13;
    int r = i & 8191;       // b*512 + col
    int col = r & 511;
    const float* h0 = dir ? h0b : h0f;
    hst[(size_t)dir * 4 * 8192 + r] = f2bf(h0[col]);
  }
  if (i < 64) tags[i] = 0;  // tag==0 means h(0) published
}

// ---------------- cast x to bf16 ----------------
__global__ void cast_x(const float* __restrict__ x, short* __restrict__ xb) {
  int i = (blockIdx.x * 256 + threadIdx.x) * 4;
  f4v v = *reinterpret_cast<const f4v*>(x + i);
  s4v o;
#pragma unroll
  for (int j = 0; j < 4; ++j) o[j] = f2bf(v[j]);
  *reinterpret_cast<s4v*>(xb + i) = o;
}

// ---------------- cast/split weights ----------------
__global__ void cast_w(const float* __restrict__ wf, const float* __restrict__ wb,
                       short* __restrict__ wxb, short* __restrict__ whb) {
  int e = blockIdx.x * 256 + threadIdx.x;  // < 1536*1536
  int dir = blockIdx.y;
  const float* w = dir ? wb : wf;
  int n = e / 1536;
  int k = e - n * 1536;
  short v = f2bf(w[e]);
  if (k < 1024)
    wxb[((size_t)(dir * 1536 + n)) * 1024 + k] = v;
  else
    whb[((size_t)(dir * 1536 + n)) * 512 + (k - 1024)] = v;
}

// ---------------- input GEMM: C = Xb @ Wxb^T, scattered to Xg[dir][t][ng][b] ----
__global__ __launch_bounds__(256) void gemm_in(const short* __restrict__ Xb,
                                               const short* __restrict__ Wxb,
                                               short* __restrict__ Xg) {
  __shared__ short As[128 * 72];
  __shared__ short Bs[128 * 72];
  int tid = threadIdx.x;
  int lane = tid & 63;
  int lr = lane & 15, quad = lane >> 4;
  int widx = tid >> 6;
  int wr = widx >> 1, wc = widx & 1;
  int bm = blockIdx.x, bn = blockIdx.y;

  f4v acc[4][4];
#pragma unroll
  for (int a = 0; a < 4; ++a)
#pragma unroll
    for (int b = 0; b < 4; ++b) acc[a][b] = {0.f, 0.f, 0.f, 0.f};

  const short* Arow = Xb + (size_t)bm * 128 * 1024;
  const short* Brow = Wxb + (size_t)bn * 128 * 1024;

  for (int kt = 0; kt < 16; ++kt) {
#pragma unroll
    for (int c = 0; c < 4; ++c) {
      int fl = c * 2048 + tid * 8;
      int row = fl >> 6, col = fl & 63;
      *reinterpret_cast<s8v*>(&As[row * 72 + col]) =
          *reinterpret_cast<const s8v*>(Arow + row * 1024 + kt * 64 + col);
      *reinterpret_cast<s8v*>(&Bs[row * 72 + col]) =
          *reinterpret_cast<const s8v*>(Brow + row * 1024 + kt * 64 + col);
    }
    __syncthreads();
#pragma unroll
    for (int kk = 0; kk < 2; ++kk) {
      s8v af[4], bfv[4];
#pragma unroll
      for (int mi = 0; mi < 4; ++mi)
        af[mi] = *reinterpret_cast<const s8v*>(&As[(wr * 64 + mi * 16 + lr) * 72 + kk * 32 + quad * 8]);
#pragma unroll
      for (int ni = 0; ni < 4; ++ni)
        bfv[ni] = *reinterpret_cast<const s8v*>(&Bs[(wc * 64 + ni * 16 + lr) * 72 + kk * 32 + quad * 8]);
#pragma unroll
      for (int mi = 0; mi < 4; ++mi)
#pragma unroll
        for (int ni = 0; ni < 4; ++ni)
          acc[mi][ni] = __builtin_amdgcn_mfma_f32_16x16x32_bf16(af[mi], bfv[ni], acc[mi][ni], 0, 0, 0);
    }
    __syncthreads();
  }

  int ngbase = bn * 128;
  int dir = (ngbase >= 1536) ? 1 : 0;
  int ng0 = ngbase - dir * 1536;
#pragma unroll
  for (int mi = 0; mi < 4; ++mi) {
#pragma unroll
    for (int ni = 0; ni < 4; ++ni) {
      int colg = ng0 + wc * 64 + ni * 16 + lr;
#pragma unroll
      for (int r = 0; r < 4; ++r) {
        int m = bm * 128 + wr * 64 + mi * 16 + quad * 4 + r;  // m = b*512 + t
        int b = m >> 9, t = m & 511;
        Xg[(((size_t)(dir * 512 + t)) * 1536 + colg) * 16 + b] = f2bf(acc[mi][ni][r]);
      }
    }
  }
}

// ---------------- recurrence ----------------
// 64 blocks x 64 threads (1 wave each); wave wg=blockIdx: dir=wg>>5, slice=wg&31.
// Wave owns h-cols [16*slice,16*slice+16). Wh in 192 VGPRs. h exchanged through
// 4-slot bf16 ring + per-slice tag line, all sc0sc1 (IF-served, placement-free).
__global__ __launch_bounds__(64, 1) void lstm_rec(
    const short* __restrict__ Whb, const short* __restrict__ Xg,
    const float* __restrict__ bfw, const float* __restrict__ bbw,
    const float* __restrict__ c0f, const float* __restrict__ c0b,
    short* __restrict__ hst, u32* __restrict__ tags, float* __restrict__ out) {
  int lane = threadIdx.x & 63;
  int lr = lane & 15, quad = lane >> 4;
  int wg = blockIdx.x;
  int dir = wg >> 5;
  int slice = wg & 31;
  int col16 = slice * 16;

  // Persistent B fragments (normal cached loads)
  const short* Whd = Whb + (size_t)dir * 1536 * 512;
  s8v Bw[3][16];
#pragma unroll
  for (int g = 0; g < 3; ++g) {
    const short* rp = Whd + (size_t)(g * 512 + col16 + lr) * 512 + quad * 8;
#pragma unroll
    for (int k = 0; k < 16; ++k) Bw[g][k] = *reinterpret_cast<const s8v*>(rp + k * 32);
  }

  const float* bias = dir ? bbw : bfw;
  float bi = bias[col16 + lr];
  float bj = bias[512 + col16 + lr];
  float bo = bias[1024 + col16 + lr];

  const float* c0 = dir ? c0b : c0f;
  float cst[4];
  {
    float c0v = c0[col16 + lr];
#pragma unroll
    for (int r = 0; r < 4; ++r) cst[r] = c0v;
  }

  short* hring = hst + (size_t)dir * 4 * 8192;  // 4 frames of [16 rows][512 cols] bf16
  u32* tg = tags + dir * 32;
  const short* xgbase = Xg + (size_t)dir * 512 * 1536 * 16;

  // First Xg prefetch (t for s=0)
  int t0 = dir ? 511 : 0;
  const short* xgp = xgbase + (size_t)t0 * 1536 * 16;
  us4 xiv = *reinterpret_cast<const us4*>(xgp + (col16 + lr) * 16 + quad * 4);
  us4 xjv = *reinterpret_cast<const us4*>(xgp + (512 + col16 + lr) * 16 + quad * 4);
  us4 xov = *reinterpret_cast<const us4*>(xgp + (1024 + col16 + lr) * 16 + quad * 4);

  for (int s = 0; s < 512; ++s) {
    int t = dir ? (511 - s) : s;

    // --- detect: one 4B tag load per lane + ballot (retry period ~1 RTT) ---
    for (;;) {
      int tv = (int)__hip_atomic_load(&tg[lane & 31], __ATOMIC_RELAXED,
                                      __HIP_MEMORY_SCOPE_AGENT);
      if (__ballot(tv >= s) == ~0ull) break;
    }

    // --- bulk fetch: 16 pipelined dwordx4 sc0sc1 loads, one vmcnt(0) ---
    const char* hp = (const char*)(hring + (size_t)(s & 3) * 8192) + lr * 1024 + quad * 16;
    s8v d0, d1, d2, d3, d4, d5, d6, d7, d8, d9, d10, d11, d12, d13, d14, d15;
    asm volatile(
        "global_load_dwordx4 %0, %16, off sc0 sc1\n\t"
        "global_load_dwordx4 %1, %16, off offset:64 sc0 sc1\n\t"
        "global_load_dwordx4 %2, %16, off offset:128 sc0 sc1\n\t"
        "global_load_dwordx4 %3, %16, off offset:192 sc0 sc1\n\t"
        "global_load_dwordx4 %4, %16, off offset:256 sc0 sc1\n\t"
        "global_load_dwordx4 %5, %16, off offset:320 sc0 sc1\n\t"
        "global_load_dwordx4 %6, %16, off offset:384 sc0 sc1\n\t"
        "global_load_dwordx4 %7, %16, off offset:448 sc0 sc1\n\t"
        "global_load_dwordx4 %8, %16, off offset:512 sc0 sc1\n\t"
        "global_load_dwordx4 %9, %16, off offset:576 sc0 sc1\n\t"
        "global_load_dwordx4 %10, %16, off offset:640 sc0 sc1\n\t"
        "global_load_dwordx4 %11, %16, off offset:704 sc0 sc1\n\t"
        "global_load_dwordx4 %12, %16, off offset:768 sc0 sc1\n\t"
        "global_load_dwordx4 %13, %16, off offset:832 sc0 sc1\n\t"
        "global_load_dwordx4 %14, %16, off offset:896 sc0 sc1\n\t"
        "global_load_dwordx4 %15, %16, off offset:960 sc0 sc1\n\t"
        "s_waitcnt vmcnt(0)"
        : "=v"(d0), "=v"(d1), "=v"(d2), "=v"(d3), "=v"(d4), "=v"(d5),
          "=v"(d6), "=v"(d7), "=v"(d8), "=v"(d9), "=v"(d10), "=v"(d11),
          "=v"(d12), "=v"(d13), "=v"(d14), "=v"(d15)
        : "v"(hp)
        : "memory");

    // --- MFMA: 48 x 16x16x32, acc in C-layout ---
    f4v a0 = {0.f, 0.f, 0.f, 0.f};
    f4v a1 = {0.f, 0.f, 0.f, 0.f};
    f4v a2 = {0.f, 0.f, 0.f, 0.f};
    s8v av[16] = {d0, d1, d2, d3, d4, d5, d6, d7, d8, d9, d10, d11, d12, d13, d14, d15};
#pragma unroll
    for (int k = 0; k < 16; ++k) {
      a0 = __builtin_amdgcn_mfma_f32_16x16x32_bf16(av[k], Bw[0][k], a0, 0, 0, 0);
      a1 = __builtin_amdgcn_mfma_f32_16x16x32_bf16(av[k], Bw[1][k], a1, 0, 0, 0);
      a2 = __builtin_amdgcn_mfma_f32_16x16x32_bf16(av[k], Bw[2][k], a2, 0, 0, 0);
    }

    // --- elementwise (C-layout: row=quad*4+r, col=col16+lr) ---
    float hn[4];
    u32 hv[4];
#pragma unroll
    for (int r = 0; r < 4; ++r) {
      float gi = a0[r] + bf2f(xiv[r]) + bi;
      float gj = a1[r] + bf2f(xjv[r]) + bj;
      float go = a2[r] + bf2f(xov[r]) + bo;
      float ii = sigmoidf_(gi);
      float jt = tanhf_(gj);
      float oo = sigmoidf_(go);
      cst[r] = (1.0f - ii) * cst[r] + ii * jt;
      hn[r] = tanhf_(cst[r]) * oo;
      hv[r] = (u32)(unsigned short)f2bf(hn[r]);
    }

    // --- publish: 4 bf16 stores (sc0sc1) -> drain -> tag store (fire&forget) ---
    {
      short* hd = hring + (size_t)((s + 1) & 3) * 8192;
      const short* hsp = hd + (quad * 4) * 512 + col16 + lr;  // r=0 row; +r*1024B
      asm volatile(
          "global_store_short %4, %0, off sc0 sc1\n\t"
          "global_store_short %4, %1, off offset:1024 sc0 sc1\n\t"
          "global_store_short %4, %2, off offset:2048 sc0 sc1\n\t"
          "global_store_short %4, %3, off offset:3072 sc0 sc1\n\t"
          "s_waitcnt vmcnt(0)"
          :: "v"(hv[0]), "v"(hv[1]), "v"(hv[2]), "v"(hv[3]), "v"(hsp)
          : "memory");
      if (lane == 0)
        __hip_atomic_store(&tg[slice], (u32)(s + 1), __ATOMIC_RELAXED,
                           __HIP_MEMORY_SCOPE_AGENT);
    }

    // --- off-critical-path: output store + next-step Xg prefetch ---
#pragma unroll
    for (int r = 0; r < 4; ++r)
      out[((size_t)(quad * 4 + r) * 512 + t) * 1024 + dir * 512 + col16 + lr] = hn[r];

    if (s < 511) {
      int tn = dir ? (511 - (s + 1)) : (s + 1);
      const short* xgn = xgbase + (size_t)tn * 1536 * 16;
      xiv = *reinterpret_cast<const us4*>(xgn + (col16 + lr) * 16 + quad * 4);
      xjv = *reinterpret_cast<const us4*>(xgn + (512 + col16 + lr) * 16 + quad * 4);
      xov = *reinterpret_cast<const us4*>(xgn + (1024 + col16 + lr) * 16 + quad * 4);
    }
  }
}

extern "C" void kernel_launch(void* const* d_in, const int* in_sizes, int n_in,
                              void* d_out, int out_size, void* d_ws, size_t ws_size,
                              hipStream_t stream) {
  const float* x    = (const float*)d_in[0];
  const float* wfw  = (const float*)d_in[1];
  const float* bfw  = (const float*)d_in[2];
  const float* wbw  = (const float*)d_in[3];
  const float* bbw  = (const float*)d_in[4];
  const float* h0f  = (const float*)d_in[5];
  const float* h0b  = (const float*)d_in[6];
  const float* c0f  = (const float*)d_in[7];
  const float* c0b  = (const float*)d_in[8];
  float* out = (float*)d_out;

  unsigned char* ws = (unsigned char*)d_ws;
  short* Xbf  = (short*)(ws + XBF_OFF);
  short* Wxbf = (short*)(ws + WXBF_OFF);
  short* Whbf = (short*)(ws + WHBF_OFF);
  short* Xg   = (short*)(ws + XG_OFF);
  short* hst  = (short*)(ws + HST_OFF);
  u32*   tags = (u32*)(ws + TAG_OFF);

  init_state<<<64, 256, 0, stream>>>(h0f, h0b, hst, tags);
  cast_x<<<8192, 256, 0, stream>>>(x, Xbf);
  cast_w<<<dim3(9216, 2), 256, 0, stream>>>(wfw, wbw, Wxbf, Whbf);
  gemm_in<<<dim3(64, 24), 256, 0, stream>>>(Xbf, Wxbf, Xg);
  lstm_rec<<<64, 64, 0, stream>>>(Whbf, Xg, bfw, bbw, c0f, c0b, hst, tags, out);
}